// Round 3
// baseline (441.137 us; speedup 1.0000x reference)
//
#include <hip/hip_runtime.h>
#include <stdint.h>
#include <stddef.h>

typedef unsigned short u16;
typedef __bf16 bf16t;
typedef bf16t bf16x8 __attribute__((ext_vector_type(8)));
typedef u16 u16x8 __attribute__((ext_vector_type(8)));
typedef u16 u16x4 __attribute__((ext_vector_type(4)));
typedef float f32x4 __attribute__((ext_vector_type(4)));

// ---------- helpers ----------
__device__ __forceinline__ float bf2f(u16 u) {
  unsigned int x = ((unsigned int)u) << 16;
  return __builtin_bit_cast(float, x);
}
__device__ __forceinline__ u16 f2bf(float f) {
  unsigned int x = __builtin_bit_cast(unsigned int, f);
  x += 0x7fffu + ((x >> 16) & 1u);
  return (u16)(x >> 16);
}
__device__ __forceinline__ u16x8 ld8(const u16* p) { return *(const u16x8*)p; }

__device__ __forceinline__ f32x4 mfma_bf16(u16x8 a, u16x8 b, f32x4 c) {
  return __builtin_amdgcn_mfma_f32_16x16x32_bf16(
      __builtin_bit_cast(bf16x8, a), __builtin_bit_cast(bf16x8, b), c, 0, 0, 0);
}
__device__ __forceinline__ void g2lds16(const u16* g, u16* l) {
  __builtin_amdgcn_global_load_lds(
      (const __attribute__((address_space(1))) unsigned int*)g,
      (__attribute__((address_space(3))) unsigned int*)l, 16, 0, 0);
}
__device__ __forceinline__ void stc(u16* p, float v) { *p = f2bf(v); }
__device__ __forceinline__ void stc(float* p, float v) { *p = v; }

// ---------- constants ----------
// B=8 K=1024 D=256 H=8 hd=32 R=4 L=1028 Ltok=B*L=8224 Mpad=8320 (65*128)
// keys padded to 1056 (33*32). All external f32; internals bf16 for MFMA.

// ---------- kernel 0: convert f32 weights -> bf16 workspace ----------
// regions (elements): cWqkv 196608 | tWqkv 196608 | cWo 65536 | tWo 65536
//                     | W1 262144 | W2 262144   — each a multiple of 1024,
// so each 256-thread block (4 el/thread) maps to exactly one region.
__global__ __launch_bounds__(256) void cvt_kernel(
    const float* __restrict__ s0, const float* __restrict__ s1,
    const float* __restrict__ s2, const float* __restrict__ s3,
    const float* __restrict__ s4, const float* __restrict__ s5,
    u16* __restrict__ d0, u16* __restrict__ d1, u16* __restrict__ d2,
    u16* __restrict__ d3, u16* __restrict__ d4, u16* __restrict__ d5)
{
  const int blk = blockIdx.x;
  const float* s; u16* d; int lb;
  if (blk < 192)      { s = s0; d = d0; lb = blk; }
  else if (blk < 384) { s = s1; d = d1; lb = blk - 192; }
  else if (blk < 448) { s = s2; d = d2; lb = blk - 384; }
  else if (blk < 512) { s = s3; d = d3; lb = blk - 448; }
  else if (blk < 768) { s = s4; d = d4; lb = blk - 512; }
  else                { s = s5; d = d5; lb = blk - 768; }
  const size_t e = ((size_t)lb * 256 + threadIdx.x) * 4;
  const f32x4 v = *(const f32x4*)(s + e);
  u16x4 o;
  #pragma unroll
  for (int j = 0; j < 4; ++j) o[j] = f2bf(v[j]);
  *(u16x4*)(d + e) = o;
}

// ---------- kernel 1: embed + rope2d + concat registers + LN + mask ----------
// grid 8320: blocks >= 8224 only zero-fill the xn pad rows (so downstream
// GEMM/attention never reads undefined workspace — NaN-poison hazard).
__global__ __launch_bounds__(256) void prep_kernel(
    const float* __restrict__ x, const int* __restrict__ coords,
    const int* __restrict__ labels, const float* __restrict__ tgt_e,
    const float* __restrict__ ctx_e, const float* __restrict__ regs,
    const float* __restrict__ rope, const float* __restrict__ g,
    const float* __restrict__ bt, float* __restrict__ x0,
    u16* __restrict__ xn, float* __restrict__ maskb)
{
  const int t = blockIdx.x;            // 0..8319
  const int d = threadIdx.x;           // 0..255
  if (t >= 8224) {                     // pad rows: defined zeros
    xn[(size_t)t * 256 + d] = 0;
    return;
  }
  const int b = t / 1028, l = t - b * 1028;
  float v;
  bool allowed;
  if (l < 4) {
    v = regs[l * 256 + d] + ctx_e[d];
    allowed = true;
  } else {
    const int p = l - 4;
    const bool ic = labels[b * 1024 + p] > 0;
    allowed = ic;
    const float* emb = ic ? ctx_e : tgt_e;
    const int cy = coords[(b * 1024 + p) * 2 + 0];
    const int cx = coords[(b * 1024 + p) * 2 + 1];
    float fy = fminf(fmaxf(((float)cy / 224.0f) * 1023.0f, 0.0f), 1023.0f);
    float fx = fminf(fmaxf(((float)cx / 224.0f) * 1023.0f, 0.0f), 1023.0f);
    const int yi = (int)fy, xi = (int)fx;
    const int pairi = (d & 127) >> 1;      // 0..63
    const bool second = d >= 128;          // second half uses y rotation
    const int ci = second ? yi : xi;
    const float c = rope[ci * 128 + pairi * 2 + 0];
    const float s = rope[ci * 128 + pairi * 2 + 1];
    const int base = (b * 1024 + p) * 256;
    const int i0 = (second ? 128 : 0) + pairi * 2;
    const float p0 = x[base + i0] + emb[i0];
    const float p1 = x[base + i0 + 1] + emb[i0 + 1];
    v = (d & 1) ? (p0 * s + p1 * c) : (p0 * c - p1 * s);
  }
  x0[(size_t)t * 256 + d] = v;
  if (d == 0) maskb[b * 1056 + l] = allowed ? 0.0f : -1e30f;
  if (d == 1 && l < 28) maskb[b * 1056 + 1028 + l] = -1e30f;  // key pad slots

  // LayerNorm over 256 elements (4 waves)
  __shared__ float sb[8];
  float s1 = v;
  #pragma unroll
  for (int off = 1; off < 64; off <<= 1) s1 += __shfl_xor(s1, off);
  const int w = threadIdx.x >> 6, lane = threadIdx.x & 63;
  if (lane == 0) sb[w] = s1;
  __syncthreads();
  const float mean = (sb[0] + sb[1] + sb[2] + sb[3]) * (1.0f / 256.0f);
  const float dv = v - mean;
  float s2 = dv * dv;
  #pragma unroll
  for (int off = 1; off < 64; off <<= 1) s2 += __shfl_xor(s2, off);
  if (lane == 0) sb[4 + w] = s2;
  __syncthreads();
  const float var = (sb[4] + sb[5] + sb[6] + sb[7]) * (1.0f / 256.0f);
  xn[(size_t)t * 256 + d] = f2bf(dv * rsqrtf(var + 1e-5f) * g[d] + bt[d]);
}

// ---------- generic GEMM: C[M,N] = A[M,K] @ W[N,K]^T + bias, m97-style ----------
// EPI: 0 = store; 1 = gelu(exact) store; 2 = + resid (f32) store. CT: u16|float
template <int EPI, typename CT>
__global__ __launch_bounds__(256) void gemm_bt(
    const u16* __restrict__ A, int lda, const u16* __restrict__ W, int K,
    const float* __restrict__ bias, CT* __restrict__ C, int ldc, int M,
    const float* __restrict__ resid)
{
  __shared__ u16 As[128 * 32];
  __shared__ u16 Bs[128 * 32];
  const int tid = threadIdx.x, lane = tid & 63, w = tid >> 6;
  const int quad = lane >> 4, r = lane & 15;
  const int wm = w >> 1, wn = w & 1;
  const int mbase = blockIdx.y * 128, nbase = blockIdx.x * 128;
  const int rA = lane >> 2, cA = (lane & 3) * 8;

  f32x4 acc[4][4];
  #pragma unroll
  for (int i = 0; i < 4; ++i)
    #pragma unroll
    for (int j = 0; j < 4; ++j) acc[i][j] = (f32x4){0.f, 0.f, 0.f, 0.f};

  const int nkt = K >> 5;
  for (int kt = 0; kt < nkt; ++kt) {
    const int k0 = kt * 32;
    #pragma unroll
    for (int j = 0; j < 2; ++j) {
      const int rr = w * 32 + j * 16;
      g2lds16(&A[(size_t)(mbase + rr + rA) * lda + k0 + cA], &As[rr * 32]);
      g2lds16(&W[(size_t)(nbase + rr + rA) * K + k0 + cA], &Bs[rr * 32]);
    }
    __syncthreads();
    u16x8 av[4], bv[4];
    #pragma unroll
    for (int mi = 0; mi < 4; ++mi) av[mi] = ld8(&As[(wm * 64 + mi * 16 + r) * 32 + quad * 8]);
    #pragma unroll
    for (int ni = 0; ni < 4; ++ni) bv[ni] = ld8(&Bs[(wn * 64 + ni * 16 + r) * 32 + quad * 8]);
    #pragma unroll
    for (int mi = 0; mi < 4; ++mi)
      #pragma unroll
      for (int ni = 0; ni < 4; ++ni)
        acc[mi][ni] = mfma_bf16(av[mi], bv[ni], acc[mi][ni]);
    __syncthreads();
  }

  #pragma unroll
  for (int mi = 0; mi < 4; ++mi) {
    #pragma unroll
    for (int ni = 0; ni < 4; ++ni) {
      const int col = nbase + wn * 64 + ni * 16 + r;
      const float bs = bias[col];
      const int row0 = mbase + wm * 64 + mi * 16 + quad * 4;
      #pragma unroll
      for (int i = 0; i < 4; ++i) {
        const int rr2 = row0 + i;
        if (rr2 < M) {
          float v = acc[mi][ni][i] + bs;
          if (EPI == 1) v = 0.5f * v * (1.0f + erff(v * 0.70710678118654752f));
          if (EPI == 2) v += resid[(size_t)rr2 * ldc + col];
          stc(&C[(size_t)rr2 * ldc + col], v);
        }
      }
    }
  }
}

// ---------- flash attention (one branch), zero-key folded into init ----------
// qkv: [8320][768] bf16 rows b*1028+l, q at +0, k at +256, v at +512 (head h: +h*32)
// grid: (17 qblocks of 64 rows, 8 heads, 8 batches); 4 waves; wave w owns 16 q rows.
__global__ __launch_bounds__(256) void attn_kernel(
    const u16* __restrict__ qkv, const float* __restrict__ bqkv,
    const float* __restrict__ maskb, u16* __restrict__ obuf)
{
  const int qb = blockIdx.x, h = blockIdx.y, b = blockIdx.z;
  const int tid = threadIdx.x, lane = tid & 63, w = tid >> 6;
  const int quad = lane >> 4, r = lane & 15;
  const float scale = 0.17677669529663687f;  // 1/sqrt(32)

  __shared__ u16 Ks[32 * 32];        // [key][dim]
  __shared__ u16 Vt[32 * 40];        // [dim][key], padded stride 40
  __shared__ u16 Ps[4][16 * 32];     // wave-private P round-trip
  __shared__ float maskS[1056];

  for (int i = tid; i < 1056; i += 256) maskS[i] = maskb[b * 1056 + i];

  // Q fragment: A layout, rows r of this wave's 16-row strip
  const int lq = qb * 64 + w * 16 + r;
  const size_t qrow = (size_t)b * 1028 + lq;      // padded buffer: always in-bounds
  const u16x8 qf = ld8(&qkv[qrow * 768 + h * 32 + quad * 8]);

  // zero-key init: score0 = q . bk / sqrt(hd); l=1; acc = bv   (bk/bv f32)
  float s0 = 0.f;
  #pragma unroll
  for (int j = 0; j < 8; ++j) s0 += bf2f(qf[j]) * bqkv[256 + h * 32 + quad * 8 + j];
  s0 *= scale;
  s0 += __shfl_xor(s0, 16);
  s0 += __shfl_xor(s0, 32);                 // lane now holds s0 for row (lane&15)
  float m_[4], l_[4];
  #pragma unroll
  for (int i = 0; i < 4; ++i) { m_[i] = __shfl(s0, quad * 4 + i); l_[i] = 1.0f; }
  const float v00 = bqkv[512 + h * 32 + r];
  const float v01 = bqkv[512 + h * 32 + 16 + r];
  f32x4 acc0, acc1;
  #pragma unroll
  for (int i = 0; i < 4; ++i) { acc0[i] = v00; acc1[i] = v01; }

  const int cc = tid & 127, key = cc >> 2, dc = (cc & 3) * 8;

  for (int kt = 0; kt < 33; ++kt) {
    __syncthreads();   // protect Ks/Vt reuse (and initial maskS staging)
    const size_t krow = ((size_t)b * 1028 + kt * 32 + key) * 768;
    if (tid < 128) {
      *(u16x8*)&Ks[key * 32 + dc] = ld8(&qkv[krow + 256 + h * 32 + dc]);
    } else {
      const u16x8 vv = ld8(&qkv[krow + 512 + h * 32 + dc]);
      #pragma unroll
      for (int j = 0; j < 8; ++j) Vt[(dc + j) * 40 + key] = vv[j];
    }
    __syncthreads();

    const u16x8 kf0 = ld8(&Ks[r * 32 + quad * 8]);
    const u16x8 kf1 = ld8(&Ks[(16 + r) * 32 + quad * 8]);
    const f32x4 z = {0.f, 0.f, 0.f, 0.f};
    const f32x4 sv0 = mfma_bf16(qf, kf0, z);
    const f32x4 sv1 = mfma_bf16(qf, kf1, z);
    const float mb0 = maskS[kt * 32 + r];
    const float mb1 = maskS[kt * 32 + 16 + r];
    float sc0[4], sc1[4], rm[4];
    #pragma unroll
    for (int i = 0; i < 4; ++i) {
      sc0[i] = sv0[i] * scale + mb0;
      sc1[i] = sv1[i] * scale + mb1;
      rm[i] = fmaxf(sc0[i], sc1[i]);
    }
    #pragma unroll
    for (int off = 1; off < 16; off <<= 1) {
      #pragma unroll
      for (int i = 0; i < 4; ++i) rm[i] = fmaxf(rm[i], __shfl_xor(rm[i], off));
    }
    float p0[4], p1[4], rs[4];
    #pragma unroll
    for (int i = 0; i < 4; ++i) {
      const float mn = fmaxf(m_[i], rm[i]);
      const float al = __expf(m_[i] - mn);
      m_[i] = mn;
      p0[i] = __expf(sc0[i] - mn);
      p1[i] = __expf(sc1[i] - mn);
      rs[i] = p0[i] + p1[i];
      acc0[i] *= al;
      acc1[i] *= al;
      l_[i] *= al;
    }
    #pragma unroll
    for (int off = 1; off < 16; off <<= 1) {
      #pragma unroll
      for (int i = 0; i < 4; ++i) rs[i] += __shfl_xor(rs[i], off);
    }
    #pragma unroll
    for (int i = 0; i < 4; ++i) {
      l_[i] += rs[i];
      Ps[w][(quad * 4 + i) * 32 + r] = f2bf(p0[i]);         // C-layout -> LDS
      Ps[w][(quad * 4 + i) * 32 + 16 + r] = f2bf(p1[i]);
    }
    const u16x8 pf = ld8(&Ps[w][r * 32 + quad * 8]);        // LDS -> A-layout
    const u16x8 vf0 = ld8(&Vt[r * 40 + quad * 8]);
    const u16x8 vf1 = ld8(&Vt[(16 + r) * 40 + quad * 8]);
    acc0 = mfma_bf16(pf, vf0, acc0);
    acc1 = mfma_bf16(pf, vf1, acc1);
  }

  const int row0 = qb * 64 + w * 16 + quad * 4;
  #pragma unroll
  for (int i = 0; i < 4; ++i) {
    const int rl = row0 + i;
    if (rl < 1028) {
      const size_t orow = (size_t)b * 1028 + rl;
      obuf[orow * 256 + h * 32 + r] = f2bf(acc0[i] / l_[i]);
      obuf[orow * 256 + h * 32 + 16 + r] = f2bf(acc1[i] / l_[i]);
    }
  }
}

// ---------- branch select + residual + LN (drops register rows) ----------
__global__ __launch_bounds__(256) void select_ln_kernel(
    const float* __restrict__ x0, const u16* __restrict__ po_c,
    const u16* __restrict__ po_t, const int* __restrict__ labels,
    const float* __restrict__ g, const float* __restrict__ bt,
    float* __restrict__ x1, u16* __restrict__ hln)
{
  const int t = blockIdx.x;                   // 0..8191
  const int b = t >> 10, p = t & 1023;
  const int d = threadIdx.x;
  const size_t row = (size_t)b * 1028 + 4 + p;
  const bool ic = labels[t] > 0;
  const u16* po = ic ? po_c : po_t;
  const float v = x0[row * 256 + d] + bf2f(po[row * 256 + d]);
  x1[(size_t)t * 256 + d] = v;
  __shared__ float sb[8];
  float s1 = v;
  #pragma unroll
  for (int off = 1; off < 64; off <<= 1) s1 += __shfl_xor(s1, off);
  const int w = threadIdx.x >> 6, lane = threadIdx.x & 63;
  if (lane == 0) sb[w] = s1;
  __syncthreads();
  const float mean = (sb[0] + sb[1] + sb[2] + sb[3]) * (1.0f / 256.0f);
  const float dv = v - mean;
  float s2 = dv * dv;
  #pragma unroll
  for (int off = 1; off < 64; off <<= 1) s2 += __shfl_xor(s2, off);
  if (lane == 0) sb[4 + w] = s2;
  __syncthreads();
  const float var = (sb[4] + sb[5] + sb[6] + sb[7]) * (1.0f / 256.0f);
  hln[(size_t)t * 256 + d] = f2bf(dv * rsqrtf(var + 1e-5f) * g[d] + bt[d]);
}

// ---------- launch ----------
extern "C" void kernel_launch(void* const* d_in, const int* in_sizes, int n_in,
                              void* d_out, int out_size, void* d_ws, size_t ws_size,
                              hipStream_t stream) {
  const float* x      = (const float*)d_in[0];
  const int*   coords = (const int*)d_in[1];
  const int*   labels = (const int*)d_in[2];
  const float* tgt_e  = (const float*)d_in[3];
  const float* ctx_e  = (const float*)d_in[4];
  const float* regs   = (const float*)d_in[5];
  const float* rope   = (const float*)d_in[6];
  const float* ng     = (const float*)d_in[7];
  const float* nb     = (const float*)d_in[8];
  const float* cWqkv  = (const float*)d_in[9];
  const float* cbqkv  = (const float*)d_in[10];
  const float* cWo    = (const float*)d_in[11];
  const float* cbo    = (const float*)d_in[12];
  const float* tWqkv  = (const float*)d_in[13];
  const float* tbqkv  = (const float*)d_in[14];
  const float* tWo    = (const float*)d_in[15];
  const float* tbo    = (const float*)d_in[16];
  const float* mg     = (const float*)d_in[17];
  const float* mbeta  = (const float*)d_in[18];
  const float* W1     = (const float*)d_in[19];
  const float* b1     = (const float*)d_in[20];
  const float* W2     = (const float*)d_in[21];
  const float* b2     = (const float*)d_in[22];

  char* ws = (char*)d_ws;
  // layout (bytes): total 61,473,792
  float* x0    = (float*)(ws + 0);           // 8224x256 f32   -> 8,421,376
  u16*   xn    = (u16*)  (ws + 8421376);     // 8320x256 bf16  -> 12,681,216
  float* maskb = (float*)(ws + 12681216);    // 8x1056 f32     -> 12,715,008
  u16*   wqc   = (u16*)  (ws + 12715008);    // 768x256 bf16
  u16*   wqt   = (u16*)  (ws + 13108224);
  u16*   woc   = (u16*)  (ws + 13501440);    // 256x256 bf16
  u16*   wot   = (u16*)  (ws + 13632512);
  u16*   w1b   = (u16*)  (ws + 13763584);    // 1024x256 bf16
  u16*   w2b   = (u16*)  (ws + 14287872);    // 256x1024 bf16 -> 14,812,160
  u16*   qkv_c = (u16*)  (ws + 14812160);    // 8320x768 bf16 -> 27,591,680
  u16*   qkv_t = (u16*)  (ws + 27591680);    //               -> 40,371,200
  u16*   o_c   = (u16*)  (ws + 40371200);    // 8320x256 bf16 -> 44,631,040
  u16*   o_t   = (u16*)  (ws + 44631040);    //               -> 48,890,880
  float* x1    = (float*)(ws + 48890880);    // 8192x256 f32  -> 57,279,488
  u16*   hln   = (u16*)  (ws + 57279488);    // 8192x256 bf16 -> 61,473,792
  // aliases into the dead qkv region (qkv_* consumed by attn before these):
  u16*   po_c  = (u16*)  (ws + 14812160);    // 8320x256 bf16
  u16*   po_t  = (u16*)  (ws + 19072000);
  u16*   hmid  = (u16*)  (ws + 23331840);    // 8192x1024 bf16 -> 40,109,056

  cvt_kernel<<<dim3(1024), 256, 0, stream>>>(cWqkv, tWqkv, cWo, tWo, W1, W2,
                                             wqc, wqt, woc, wot, w1b, w2b);
  prep_kernel<<<dim3(8320), 256, 0, stream>>>(x, coords, labels, tgt_e, ctx_e,
                                              regs, rope, ng, nb, x0, xn, maskb);
  // QKV: M=8320 so padded K/V rows read by attention are defined (finite);
  // pad A rows are zeros -> pad qkv rows = bias. Additive -1e30 mask then holds.
  gemm_bt<0, u16><<<dim3(6, 65), 256, 0, stream>>>(xn, 256, wqc, 256, cbqkv, qkv_c, 768, 8320, nullptr);
  gemm_bt<0, u16><<<dim3(6, 65), 256, 0, stream>>>(xn, 256, wqt, 256, tbqkv, qkv_t, 768, 8320, nullptr);
  attn_kernel<<<dim3(17, 8, 8), 256, 0, stream>>>(qkv_c, cbqkv, maskb, o_c);
  attn_kernel<<<dim3(17, 8, 8), 256, 0, stream>>>(qkv_t, tbqkv, maskb, o_t);
  gemm_bt<0, u16><<<dim3(2, 65), 256, 0, stream>>>(o_c, 256, woc, 256, cbo, po_c, 256, 8224, nullptr);
  gemm_bt<0, u16><<<dim3(2, 65), 256, 0, stream>>>(o_t, 256, wot, 256, tbo, po_t, 256, 8224, nullptr);
  select_ln_kernel<<<dim3(8192), 256, 0, stream>>>(x0, po_c, po_t, labels, mg, mbeta, x1, hln);
  gemm_bt<1, u16><<<dim3(8, 64), 256, 0, stream>>>(hln, 256, w1b, 256, b1, hmid, 1024, 8192, nullptr);
  gemm_bt<2, float><<<dim3(2, 64), 256, 0, stream>>>(hmid, 1024, w2b, 1024, b2, (float*)d_out, 256, 8192, x1);
}

// Round 4
// 313.190 us; speedup vs baseline: 1.4085x; 1.4085x over previous
//
#include <hip/hip_runtime.h>
#include <stdint.h>
#include <stddef.h>

typedef unsigned short u16;
typedef __bf16 bf16t;
typedef bf16t bf16x8 __attribute__((ext_vector_type(8)));
typedef u16 u16x8 __attribute__((ext_vector_type(8)));
typedef u16 u16x4 __attribute__((ext_vector_type(4)));
typedef float f32x4 __attribute__((ext_vector_type(4)));

// ---------- helpers ----------
__device__ __forceinline__ float bf2f(u16 u) {
  unsigned int x = ((unsigned int)u) << 16;
  return __builtin_bit_cast(float, x);
}
__device__ __forceinline__ u16 f2bf(float f) {
  unsigned int x = __builtin_bit_cast(unsigned int, f);
  x += 0x7fffu + ((x >> 16) & 1u);
  return (u16)(x >> 16);
}
__device__ __forceinline__ u16x8 ld8(const u16* p) { return *(const u16x8*)p; }

__device__ __forceinline__ f32x4 mfma_bf16(u16x8 a, u16x8 b, f32x4 c) {
  return __builtin_amdgcn_mfma_f32_16x16x32_bf16(
      __builtin_bit_cast(bf16x8, a), __builtin_bit_cast(bf16x8, b), c, 0, 0, 0);
}
__device__ __forceinline__ void g2lds16(const u16* g, u16* l) {
  __builtin_amdgcn_global_load_lds(
      (const __attribute__((address_space(1))) unsigned int*)g,
      (__attribute__((address_space(3))) unsigned int*)l, 16, 0, 0);
}
__device__ __forceinline__ void stc(u16* p, float v) { *p = f2bf(v); }
__device__ __forceinline__ void stc(float* p, float v) { *p = v; }

// ---------- constants ----------
// B=8 K=1024 D=256 H=8 hd=32 R=4 L=1028 Ltok=8224 Mpad=8320 (65*128)
// Compacted: per-batch query capacity 1024 (per branch), key capacity 1088.

// ---------- kernel 0: convert f32 weights -> bf16 workspace ----------
__global__ __launch_bounds__(256) void cvt_kernel(
    const float* __restrict__ s0, const float* __restrict__ s1,
    const float* __restrict__ s2, const float* __restrict__ s3,
    const float* __restrict__ s4, const float* __restrict__ s5,
    u16* __restrict__ d0, u16* __restrict__ d1, u16* __restrict__ d2,
    u16* __restrict__ d3, u16* __restrict__ d4, u16* __restrict__ d5)
{
  const int blk = blockIdx.x;
  const float* s; u16* d; int lb;
  if (blk < 192)      { s = s0; d = d0; lb = blk; }
  else if (blk < 384) { s = s1; d = d1; lb = blk - 192; }
  else if (blk < 448) { s = s2; d = d2; lb = blk - 384; }
  else if (blk < 512) { s = s3; d = d3; lb = blk - 448; }
  else if (blk < 768) { s = s4; d = d4; lb = blk - 512; }
  else                { s = s5; d = d5; lb = blk - 768; }
  const size_t e = ((size_t)lb * 256 + threadIdx.x) * 4;
  const f32x4 v = *(const f32x4*)(s + e);
  u16x4 o;
  #pragma unroll
  for (int j = 0; j < 4; ++j) o[j] = f2bf(v[j]);
  *(u16x4*)(d + e) = o;
}

// ---------- kernel 1: embed + rope2d + registers + LN ----------
__global__ __launch_bounds__(256) void prep_kernel(
    const float* __restrict__ x, const int* __restrict__ coords,
    const int* __restrict__ labels, const float* __restrict__ tgt_e,
    const float* __restrict__ ctx_e, const float* __restrict__ regs,
    const float* __restrict__ rope, const float* __restrict__ g,
    const float* __restrict__ bt, float* __restrict__ x0,
    u16* __restrict__ xn)
{
  const int t = blockIdx.x;            // 0..8319
  const int d = threadIdx.x;           // 0..255
  if (t >= 8224) {                     // pad rows: defined zeros (QKV A-tiles)
    xn[(size_t)t * 256 + d] = 0;
    return;
  }
  const int b = t / 1028, l = t - b * 1028;
  float v;
  if (l < 4) {
    v = regs[l * 256 + d] + ctx_e[d];
  } else {
    const int p = l - 4;
    const bool ic = labels[b * 1024 + p] > 0;
    const float* emb = ic ? ctx_e : tgt_e;
    const int cy = coords[(b * 1024 + p) * 2 + 0];
    const int cx = coords[(b * 1024 + p) * 2 + 1];
    float fy = fminf(fmaxf(((float)cy / 224.0f) * 1023.0f, 0.0f), 1023.0f);
    float fx = fminf(fmaxf(((float)cx / 224.0f) * 1023.0f, 0.0f), 1023.0f);
    const int yi = (int)fy, xi = (int)fx;
    const int pairi = (d & 127) >> 1;
    const bool second = d >= 128;
    const int ci = second ? yi : xi;
    const float c = rope[ci * 128 + pairi * 2 + 0];
    const float s = rope[ci * 128 + pairi * 2 + 1];
    const int base = (b * 1024 + p) * 256;
    const int i0 = (second ? 128 : 0) + pairi * 2;
    const float p0 = x[base + i0] + emb[i0];
    const float p1 = x[base + i0 + 1] + emb[i0 + 1];
    v = (d & 1) ? (p0 * s + p1 * c) : (p0 * c - p1 * s);
  }
  x0[(size_t)t * 256 + d] = v;

  __shared__ float sb[8];
  float s1 = v;
  #pragma unroll
  for (int off = 1; off < 64; off <<= 1) s1 += __shfl_xor(s1, off);
  const int w = threadIdx.x >> 6, lane = threadIdx.x & 63;
  if (lane == 0) sb[w] = s1;
  __syncthreads();
  const float mean = (sb[0] + sb[1] + sb[2] + sb[3]) * (1.0f / 256.0f);
  const float dv = v - mean;
  float s2 = dv * dv;
  #pragma unroll
  for (int off = 1; off < 64; off <<= 1) s2 += __shfl_xor(s2, off);
  if (lane == 0) sb[4 + w] = s2;
  __syncthreads();
  const float var = (sb[4] + sb[5] + sb[6] + sb[7]) * (1.0f / 256.0f);
  xn[(size_t)t * 256 + d] = f2bf(dv * rsqrtf(var + 1e-5f) * g[d] + bt[d]);
}

// ---------- kernel 2: per-batch compaction (keys + per-branch queries) ----------
__global__ __launch_bounds__(1024) void compact_kernel(
    const int* __restrict__ labels, int* __restrict__ qidx_c,
    int* __restrict__ qidx_t, int* __restrict__ qcnt_c,
    int* __restrict__ qcnt_t, int* __restrict__ kidx,
    float* __restrict__ keyb, int* __restrict__ nktb,
    int* __restrict__ slotm)
{
  const int b = blockIdx.x, tid = threadIdx.x;
  const int wave = tid >> 6, lane = tid & 63;
  const bool ic = labels[b * 1024 + tid] > 0;
  const unsigned long long mask = __ballot(ic);
  const int lower = __popcll(mask & ((1ull << lane) - 1ull));
  const int wc = __popcll(mask);
  __shared__ int wcnt[16], woff[17];
  if (lane == 0) wcnt[wave] = wc;
  // init key slots to pad defaults
  kidx[b * 1088 + tid] = b * 1028;       // register row 0 (finite data)
  keyb[b * 1088 + tid] = -1e30f;
  if (tid < 64) { kidx[b * 1088 + 1024 + tid] = b * 1028;
                  keyb[b * 1088 + 1024 + tid] = -1e30f; }
  __syncthreads();
  if (tid == 0) {
    int acc = 0;
    #pragma unroll
    for (int i = 0; i < 16; ++i) { woff[i] = acc; acc += wcnt[i]; }
    woff[16] = acc;
  }
  __syncthreads();
  const int nc = woff[16];
  const int nt = 1024 - nc;
  const int rank_c = woff[wave] + lower;
  const int rank_t = tid - woff[wave] - lower;
  const int grow = b * 1028 + 4 + tid;   // token row in 1028-space
  if (ic) {
    qidx_c[b * 1024 + rank_c] = grow;
    slotm[b * 1024 + tid] = rank_c;
    kidx[b * 1088 + 4 + rank_c] = grow;
    keyb[b * 1088 + 4 + rank_c] = 0.0f;
  } else {
    qidx_t[b * 1024 + rank_t] = grow;
    slotm[b * 1024 + tid] = rank_t;
  }
  if (tid < 4) { kidx[b * 1088 + tid] = b * 1028 + tid;
                 keyb[b * 1088 + tid] = 0.0f; }
  // pad query slots up to 64-multiple with register row (finite garbage)
  const int ncp = (nc + 63) & ~63;
  const int ntp = (nt + 63) & ~63;
  if (tid >= nc && tid < ncp) qidx_c[b * 1024 + tid] = b * 1028;
  if (tid >= nt && tid < ntp) qidx_t[b * 1024 + tid] = b * 1028;
  if (tid == 0) {
    qcnt_c[b] = nc; qcnt_t[b] = nt;
    nktb[b] = (nc + 4 + 63) >> 6;        // 64-key tiles (regs + ctx keys)
  }
}

// ---------- generic GEMM: C[M,N] = A[M,K] @ W[N,K]^T + bias ----------
// EPI: 0 = store; 1 = gelu store; 2 = +resid store. bcnt: per-batch dyn-M exit.
template <int EPI, typename CT>
__global__ __launch_bounds__(256) void gemm_bt(
    const u16* __restrict__ A, int lda, const u16* __restrict__ W, int K,
    const float* __restrict__ bias, CT* __restrict__ C, int ldc, int M,
    const float* __restrict__ resid, const int* __restrict__ bcnt)
{
  const int mbase = blockIdx.y * 128, nbase = blockIdx.x * 128;
  if (bcnt) {
    const int bb = mbase >> 10;
    const int need = (bcnt[bb] + 127) & ~127;
    if ((mbase & 1023) >= need) return;
  }
  __shared__ u16 As[128 * 32];
  __shared__ u16 Bs[128 * 32];
  const int tid = threadIdx.x, lane = tid & 63, w = tid >> 6;
  const int quad = lane >> 4, r = lane & 15;
  const int wm = w >> 1, wn = w & 1;
  const int rA = lane >> 2, cA = (lane & 3) * 8;

  f32x4 acc[4][4];
  #pragma unroll
  for (int i = 0; i < 4; ++i)
    #pragma unroll
    for (int j = 0; j < 4; ++j) acc[i][j] = (f32x4){0.f, 0.f, 0.f, 0.f};

  const int nkt = K >> 5;
  for (int kt = 0; kt < nkt; ++kt) {
    const int k0 = kt * 32;
    #pragma unroll
    for (int j = 0; j < 2; ++j) {
      const int rr = w * 32 + j * 16;
      g2lds16(&A[(size_t)(mbase + rr + rA) * lda + k0 + cA], &As[rr * 32]);
      g2lds16(&W[(size_t)(nbase + rr + rA) * K + k0 + cA], &Bs[rr * 32]);
    }
    __syncthreads();
    u16x8 av[4], bv[4];
    #pragma unroll
    for (int mi = 0; mi < 4; ++mi) av[mi] = ld8(&As[(wm * 64 + mi * 16 + r) * 32 + quad * 8]);
    #pragma unroll
    for (int ni = 0; ni < 4; ++ni) bv[ni] = ld8(&Bs[(wn * 64 + ni * 16 + r) * 32 + quad * 8]);
    #pragma unroll
    for (int mi = 0; mi < 4; ++mi)
      #pragma unroll
      for (int ni = 0; ni < 4; ++ni)
        acc[mi][ni] = mfma_bf16(av[mi], bv[ni], acc[mi][ni]);
    __syncthreads();
  }

  #pragma unroll
  for (int mi = 0; mi < 4; ++mi) {
    #pragma unroll
    for (int ni = 0; ni < 4; ++ni) {
      const int col = nbase + wn * 64 + ni * 16 + r;
      const float bs = bias[col];
      const int row0 = mbase + wm * 64 + mi * 16 + quad * 4;
      #pragma unroll
      for (int i = 0; i < 4; ++i) {
        const int rr2 = row0 + i;
        if (rr2 < M) {
          float v = acc[mi][ni][i] + bs;
          if (EPI == 1) v = 0.5f * v * (1.0f + erff(v * 0.70710678118654752f));
          if (EPI == 2) v += resid[(size_t)rr2 * ldc + col];
          stc(&C[(size_t)rr2 * ldc + col], v);
        }
      }
    }
  }
}

// ---------- kernel 3: compacted flash attention (one branch) ----------
// S^T = K·Q^T (keys on M) => scalar m,l per lane; O^T = V^T·P^T.
// grid (128, 8): x = global 64-query window (b = x>>4), y = head.
__global__ __launch_bounds__(256) void attn2_kernel(
    const u16* __restrict__ qkv, const float* __restrict__ bqkv,
    const int* __restrict__ qidx, const int* __restrict__ qcnt,
    const int* __restrict__ kidx, const float* __restrict__ keyb,
    const int* __restrict__ nktb, u16* __restrict__ obuf)
{
  const int qb = blockIdx.x, h = blockIdx.y;
  const int b = qb >> 4, qb_in = qb & 15;
  if (qb_in * 64 >= qcnt[b]) return;
  const int tid = threadIdx.x, lane = tid & 63, w = tid >> 6;
  const int quad = lane >> 4, r = lane & 15;
  const float scale = 0.17677669529663687f;  // 1/sqrt(32)

  __shared__ u16 Ks[64 * 32];        // [key][dim]
  __shared__ u16 Vt[32 * 66];        // [dim][key] stride 66 (write conflict-free)
  __shared__ u16 Ps[4][16 * 72];     // per-wave P row-major [q][key] stride 72
  __shared__ float keybS[64];

  const int qslot = qb_in * 64 + w * 16 + r;
  const int qrow = qidx[b * 1024 + qslot];
  const u16x8 qf = ld8(&qkv[(size_t)qrow * 768 + h * 32 + quad * 8]);

  // zero-key: score = q.bk*scale; l=1; acc=bv  (bqkv f32)
  float s0 = 0.f;
  #pragma unroll
  for (int j = 0; j < 8; ++j) s0 += bf2f(qf[j]) * bqkv[256 + h * 32 + quad * 8 + j];
  s0 *= scale;
  s0 += __shfl_xor(s0, 16);
  s0 += __shfl_xor(s0, 32);
  float m_ = s0, l_ = 1.0f;
  f32x4 accA, accB;                  // O^T rows d=quad*4+i (+16)
  #pragma unroll
  for (int i = 0; i < 4; ++i) {
    accA[i] = bqkv[512 + h * 32 + quad * 4 + i];
    accB[i] = bqkv[512 + h * 32 + 16 + quad * 4 + i];
  }

  const int key = tid >> 2, dc = (tid & 3) * 8;
  const int ntile = nktb[b];
  for (int t = 0; t < ntile; ++t) {
    __syncthreads();
    const int krow = kidx[b * 1088 + t * 64 + key];
    g2lds16(&qkv[(size_t)krow * 768 + 256 + h * 32 + dc], &Ks[w * 512]);
    const u16x8 vv = ld8(&qkv[(size_t)krow * 768 + 512 + h * 32 + dc]);
    #pragma unroll
    for (int j = 0; j < 8; ++j) Vt[(dc + j) * 66 + key] = vv[j];
    if (tid < 64) keybS[tid] = keyb[b * 1088 + t * 64 + tid];
    __syncthreads();

    f32x4 sT[4];
    #pragma unroll
    for (int tt = 0; tt < 4; ++tt) {
      const u16x8 kf = ld8(&Ks[(tt * 16 + r) * 32 + quad * 8]);
      sT[tt] = mfma_bf16(kf, qf, (f32x4){0.f, 0.f, 0.f, 0.f});
    }
    float rm = -3.0e38f;
    float sc[4][4];
    #pragma unroll
    for (int tt = 0; tt < 4; ++tt)
      #pragma unroll
      for (int i = 0; i < 4; ++i) {
        sc[tt][i] = sT[tt][i] * scale + keybS[tt * 16 + quad * 4 + i];
        rm = fmaxf(rm, sc[tt][i]);
      }
    rm = fmaxf(rm, __shfl_xor(rm, 16));
    rm = fmaxf(rm, __shfl_xor(rm, 32));
    const float mn = fmaxf(m_, rm);
    const float al = __expf(m_ - mn);
    m_ = mn;
    float rs = 0.f;
    u16* ps = &Ps[w][r * 72];
    #pragma unroll
    for (int tt = 0; tt < 4; ++tt) {
      u16x4 pk;
      #pragma unroll
      for (int i = 0; i < 4; ++i) {
        const float pv = __expf(sc[tt][i] - mn);
        rs += pv;
        pk[i] = f2bf(pv);
      }
      *(u16x4*)&ps[tt * 16 + quad * 4] = pk;   // b64, 2-way (free)
    }
    rs += __shfl_xor(rs, 16);
    rs += __shfl_xor(rs, 32);
    l_ = l_ * al + rs;
    #pragma unroll
    for (int i = 0; i < 4; ++i) { accA[i] *= al; accB[i] *= al; }
    #pragma unroll
    for (int kk = 0; kk < 2; ++kk) {
      const u16x8 pf = ld8(&Ps[w][r * 72 + kk * 32 + quad * 8]);
      const u16x8 vf0 = ld8(&Vt[r * 66 + kk * 32 + quad * 8]);
      const u16x8 vf1 = ld8(&Vt[(16 + r) * 66 + kk * 32 + quad * 8]);
      accA = mfma_bf16(vf0, pf, accA);
      accB = mfma_bf16(vf1, pf, accB);
    }
  }

  const float inv = 1.0f / l_;
  u16x4 oa, ob;
  #pragma unroll
  for (int i = 0; i < 4; ++i) { oa[i] = f2bf(accA[i] * inv); ob[i] = f2bf(accB[i] * inv); }
  const size_t orow = (size_t)b * 1024 + qslot;
  *(u16x4*)&obuf[orow * 256 + h * 32 + quad * 4] = oa;
  *(u16x4*)&obuf[orow * 256 + h * 32 + 16 + quad * 4] = ob;
}

// ---------- kernel 4: branch select + residual + LN ----------
__global__ __launch_bounds__(256) void select_ln_kernel(
    const float* __restrict__ x0, const u16* __restrict__ po_c,
    const u16* __restrict__ po_t, const int* __restrict__ labels,
    const int* __restrict__ slotm, const float* __restrict__ g,
    const float* __restrict__ bt, float* __restrict__ x1,
    u16* __restrict__ hln)
{
  const int t = blockIdx.x;                   // 0..8191
  const int b = t >> 10;
  const int d = threadIdx.x;
  const size_t row = (size_t)b * 1028 + 4 + (t & 1023);
  const bool ic = labels[t] > 0;
  const u16* po = ic ? po_c : po_t;
  const int slot = slotm[t];
  const float v = x0[row * 256 + d] + bf2f(po[((size_t)b * 1024 + slot) * 256 + d]);
  x1[(size_t)t * 256 + d] = v;
  __shared__ float sb[8];
  float s1 = v;
  #pragma unroll
  for (int off = 1; off < 64; off <<= 1) s1 += __shfl_xor(s1, off);
  const int w = threadIdx.x >> 6, lane = threadIdx.x & 63;
  if (lane == 0) sb[w] = s1;
  __syncthreads();
  const float mean = (sb[0] + sb[1] + sb[2] + sb[3]) * (1.0f / 256.0f);
  const float dv = v - mean;
  float s2 = dv * dv;
  #pragma unroll
  for (int off = 1; off < 64; off <<= 1) s2 += __shfl_xor(s2, off);
  if (lane == 0) sb[4 + w] = s2;
  __syncthreads();
  const float var = (sb[4] + sb[5] + sb[6] + sb[7]) * (1.0f / 256.0f);
  hln[(size_t)t * 256 + d] = f2bf(dv * rsqrtf(var + 1e-5f) * g[d] + bt[d]);
}

// ---------- launch ----------
extern "C" void kernel_launch(void* const* d_in, const int* in_sizes, int n_in,
                              void* d_out, int out_size, void* d_ws, size_t ws_size,
                              hipStream_t stream) {
  const float* x      = (const float*)d_in[0];
  const int*   coords = (const int*)d_in[1];
  const int*   labels = (const int*)d_in[2];
  const float* tgt_e  = (const float*)d_in[3];
  const float* ctx_e  = (const float*)d_in[4];
  const float* regs   = (const float*)d_in[5];
  const float* rope   = (const float*)d_in[6];
  const float* ng     = (const float*)d_in[7];
  const float* nb     = (const float*)d_in[8];
  const float* cWqkv  = (const float*)d_in[9];
  const float* cbqkv  = (const float*)d_in[10];
  const float* cWo    = (const float*)d_in[11];
  const float* cbo    = (const float*)d_in[12];
  const float* tWqkv  = (const float*)d_in[13];
  const float* tbqkv  = (const float*)d_in[14];
  const float* tWo    = (const float*)d_in[15];
  const float* tbo    = (const float*)d_in[16];
  const float* mg     = (const float*)d_in[17];
  const float* mbeta  = (const float*)d_in[18];
  const float* W1     = (const float*)d_in[19];
  const float* b1     = (const float*)d_in[20];
  const float* W2     = (const float*)d_in[21];
  const float* b2     = (const float*)d_in[22];

  char* ws = (char*)d_ws;
  float* x0     = (float*)(ws + 0);            // 8224x256 f32
  u16*   xn     = (u16*)  (ws + 8421376);      // 8320x256 bf16
  u16*   wqc    = (u16*)  (ws + 12681216);     // 768x256
  u16*   wqt    = (u16*)  (ws + 13074432);
  u16*   woc    = (u16*)  (ws + 13467648);     // 256x256
  u16*   wot    = (u16*)  (ws + 13598720);
  u16*   w1b    = (u16*)  (ws + 13729792);     // 1024x256
  u16*   w2b    = (u16*)  (ws + 14254080);     // 256x1024 -> 14,778,368
  u16*   qkv_c  = (u16*)  (ws + 14778368);     // 8320x768 -> 27,557,888
  u16*   qkv_t  = (u16*)  (ws + 27557888);     //          -> 40,337,408
  u16*   o_c    = (u16*)  (ws + 40337408);     // 8192x256 -> 44,531,712
  u16*   o_t    = (u16*)  (ws + 44531712);     //          -> 48,726,016
  float* x1     = (float*)(ws + 48726016);     // 8192x256 f32 -> 57,114,624
  u16*   hln    = (u16*)  (ws + 57114624);     // 8192x256 -> 61,308,928
  int*   qidx_c = (int*)  (ws + 61308928);     // 8192 int
  int*   qidx_t = (int*)  (ws + 61341696);
  int*   kidx   = (int*)  (ws + 61374464);     // 8x1088
  float* keyb   = (float*)(ws + 61409280);     // 8x1088
  int*   slotm  = (int*)  (ws + 61444096);     // 8192
  int*   qcnt_c = (int*)  (ws + 61476864);     // 8
  int*   qcnt_t = (int*)  (ws + 61476896);     // 8
  int*   nktb   = (int*)  (ws + 61476928);     // 8
  // aliases into dead qkv regions (qkv consumed by attn before these writes):
  u16*   po_c   = (u16*)  (ws + 14778368);     // 8192x256
  u16*   po_t   = (u16*)  (ws + 18972672);
  u16*   hmid   = (u16*)  (ws + 23166976);     // 8192x1024 -> 39,944,192

  cvt_kernel<<<dim3(1024), 256, 0, stream>>>(cWqkv, tWqkv, cWo, tWo, W1, W2,
                                             wqc, wqt, woc, wot, w1b, w2b);
  prep_kernel<<<dim3(8320), 256, 0, stream>>>(x, coords, labels, tgt_e, ctx_e,
                                              regs, rope, ng, nb, x0, xn);
  compact_kernel<<<dim3(8), 1024, 0, stream>>>(labels, qidx_c, qidx_t, qcnt_c,
                                               qcnt_t, kidx, keyb, nktb, slotm);
  gemm_bt<0, u16><<<dim3(6, 65), 256, 0, stream>>>(xn, 256, wqc, 256, cbqkv, qkv_c, 768, 8320, nullptr, nullptr);
  gemm_bt<0, u16><<<dim3(6, 65), 256, 0, stream>>>(xn, 256, wqt, 256, tbqkv, qkv_t, 768, 8320, nullptr, nullptr);
  attn2_kernel<<<dim3(128, 8), 256, 0, stream>>>(qkv_c, cbqkv, qidx_c, qcnt_c, kidx, keyb, nktb, o_c);
  attn2_kernel<<<dim3(128, 8), 256, 0, stream>>>(qkv_t, tbqkv, qidx_t, qcnt_t, kidx, keyb, nktb, o_t);
  gemm_bt<0, u16><<<dim3(2, 64), 256, 0, stream>>>(o_c, 256, woc, 256, cbo, po_c, 256, 8192, nullptr, qcnt_c);
  gemm_bt<0, u16><<<dim3(2, 64), 256, 0, stream>>>(o_t, 256, wot, 256, tbo, po_t, 256, 8192, nullptr, qcnt_t);
  select_ln_kernel<<<dim3(8192), 256, 0, stream>>>(x0, po_c, po_t, labels, slotm, mg, mbeta, x1, hln);
  gemm_bt<1, u16><<<dim3(8, 64), 256, 0, stream>>>(hln, 256, w1b, 256, b1, hmid, 1024, 8192, nullptr, nullptr);
  gemm_bt<2, float><<<dim3(2, 64), 256, 0, stream>>>(hmid, 1024, w2b, 1024, b2, (float*)d_out, 256, 8192, x1, nullptr);
}

// Round 5
// 275.112 us; speedup vs baseline: 1.6035x; 1.1384x over previous
//
#include <hip/hip_runtime.h>
#include <stdint.h>
#include <stddef.h>

typedef unsigned short u16;
typedef __bf16 bf16t;
typedef bf16t bf16x8 __attribute__((ext_vector_type(8)));
typedef u16 u16x8 __attribute__((ext_vector_type(8)));
typedef u16 u16x4 __attribute__((ext_vector_type(4)));
typedef float f32x4 __attribute__((ext_vector_type(4)));

// ---------- helpers ----------
__device__ __forceinline__ float bf2f(u16 u) {
  unsigned int x = ((unsigned int)u) << 16;
  return __builtin_bit_cast(float, x);
}
__device__ __forceinline__ u16 f2bf(float f) {
  unsigned int x = __builtin_bit_cast(unsigned int, f);
  x += 0x7fffu + ((x >> 16) & 1u);
  return (u16)(x >> 16);
}
__device__ __forceinline__ u16x8 ld8(const u16* p) { return *(const u16x8*)p; }

__device__ __forceinline__ f32x4 mfma_bf16(u16x8 a, u16x8 b, f32x4 c) {
  return __builtin_amdgcn_mfma_f32_16x16x32_bf16(
      __builtin_bit_cast(bf16x8, a), __builtin_bit_cast(bf16x8, b), c, 0, 0, 0);
}
__device__ __forceinline__ void g2lds16(const u16* g, u16* l) {
  __builtin_amdgcn_global_load_lds(
      (const __attribute__((address_space(1))) unsigned int*)g,
      (__attribute__((address_space(3))) unsigned int*)l, 16, 0, 0);
}
__device__ __forceinline__ void stc(u16* p, float v) { *p = f2bf(v); }
__device__ __forceinline__ void stc(float* p, float v) { *p = v; }

// ---------- constants ----------
// B=8 K=1024 D=256 H=8 hd=32 R=4 L=1028 Ltok=8224 Mpad=8320 (65*128)
// qkv fused: [8320][1536] = [q_c k_c v_c | q_t k_t v_t]

// ---------- kernel 0: convert f32 weights -> bf16 + concat QKV bias ----------
__global__ __launch_bounds__(256) void cvt_kernel(
    const float* __restrict__ s0, const float* __restrict__ s1,
    const float* __restrict__ s2, const float* __restrict__ s3,
    const float* __restrict__ s4, const float* __restrict__ s5,
    u16* __restrict__ d0, u16* __restrict__ d1, u16* __restrict__ d2,
    u16* __restrict__ d3, u16* __restrict__ d4, u16* __restrict__ d5,
    const float* __restrict__ cb, const float* __restrict__ tb,
    float* __restrict__ biasq)
{
  const int blk = blockIdx.x;
  if (blk >= 1024) {                       // QKV bias concat (f32)
    const int e0 = (blk - 1024) * 1024 + threadIdx.x * 4;
    #pragma unroll
    for (int j = 0; j < 4; ++j) {
      const int e = e0 + j;
      if (e < 1536) biasq[e] = e < 768 ? cb[e] : tb[e - 768];
    }
    return;
  }
  const float* s; u16* d; int lb;
  if (blk < 192)      { s = s0; d = d0; lb = blk; }
  else if (blk < 384) { s = s1; d = d1; lb = blk - 192; }
  else if (blk < 448) { s = s2; d = d2; lb = blk - 384; }
  else if (blk < 512) { s = s3; d = d3; lb = blk - 448; }
  else if (blk < 768) { s = s4; d = d4; lb = blk - 512; }
  else                { s = s5; d = d5; lb = blk - 768; }
  const size_t e = ((size_t)lb * 256 + threadIdx.x) * 4;
  const f32x4 v = *(const f32x4*)(s + e);
  u16x4 o;
  #pragma unroll
  for (int j = 0; j < 4; ++j) o[j] = f2bf(v[j]);
  *(u16x4*)(d + e) = o;
}

// ---------- kernel 1: embed + rope2d + registers + LN (wave-per-row) ----------
// 4 rows/block, lane owns 4 consecutive elements; LN via shuffles only.
__global__ __launch_bounds__(256) void prep_kernel(
    const float* __restrict__ x, const int* __restrict__ coords,
    const int* __restrict__ labels, const float* __restrict__ tgt_e,
    const float* __restrict__ ctx_e, const float* __restrict__ regs,
    const float* __restrict__ rope, const float* __restrict__ g,
    const float* __restrict__ bt, float* __restrict__ x0,
    u16* __restrict__ xn)
{
  const int wv = threadIdx.x >> 6, lane = threadIdx.x & 63;
  const int t = blockIdx.x * 4 + wv;   // 0..8319
  const int d = lane * 4;
  if (t >= 8224) {                     // pad rows: defined zeros (QKV A-tiles)
    *(u16x4*)&xn[(size_t)t * 256 + d] = (u16x4){0, 0, 0, 0};
    return;
  }
  const int b = t / 1028, l = t - b * 1028;
  f32x4 v;
  if (l < 4) {
    const f32x4 rg = *(const f32x4*)&regs[l * 256 + d];
    const f32x4 ce = *(const f32x4*)&ctx_e[d];
    #pragma unroll
    for (int j = 0; j < 4; ++j) v[j] = rg[j] + ce[j];
  } else {
    const int p = l - 4;
    const bool ic = labels[b * 1024 + p] > 0;
    const float* emb = ic ? ctx_e : tgt_e;
    const int cy = coords[(b * 1024 + p) * 2 + 0];
    const int cx = coords[(b * 1024 + p) * 2 + 1];
    const float fy = fminf(fmaxf(((float)cy / 224.0f) * 1023.0f, 0.0f), 1023.0f);
    const float fx = fminf(fmaxf(((float)cx / 224.0f) * 1023.0f, 0.0f), 1023.0f);
    const int yi = (int)fy, xi = (int)fx;
    const bool second = d >= 128;
    const int ci = second ? yi : xi;
    const int pairi = (d & 127) >> 1;                  // even pair index
    const f32x4 rr = *(const f32x4*)&rope[ci * 128 + pairi * 2];  // cA sA cB sB
    const int i0 = (second ? 128 : 0) + pairi * 2;
    const size_t base = (size_t)(b * 1024 + p) * 256;
    const f32x4 xv = *(const f32x4*)&x[base + i0];
    const f32x4 ev = *(const f32x4*)&emb[i0];
    const float p0 = xv[0] + ev[0], p1 = xv[1] + ev[1];
    const float p2 = xv[2] + ev[2], p3 = xv[3] + ev[3];
    v[0] = p0 * rr[0] - p1 * rr[1];
    v[1] = p0 * rr[1] + p1 * rr[0];
    v[2] = p2 * rr[2] - p3 * rr[3];
    v[3] = p2 * rr[3] + p3 * rr[2];
  }
  *(f32x4*)&x0[(size_t)t * 256 + d] = v;
  float s1 = v[0] + v[1] + v[2] + v[3];
  #pragma unroll
  for (int off = 1; off < 64; off <<= 1) s1 += __shfl_xor(s1, off);
  const float mean = s1 * (1.0f / 256.0f);
  f32x4 dv;
  float s2 = 0.f;
  #pragma unroll
  for (int j = 0; j < 4; ++j) { dv[j] = v[j] - mean; s2 += dv[j] * dv[j]; }
  #pragma unroll
  for (int off = 1; off < 64; off <<= 1) s2 += __shfl_xor(s2, off);
  const float rstd = rsqrtf(s2 * (1.0f / 256.0f) + 1e-5f);
  const f32x4 gv = *(const f32x4*)&g[d];
  const f32x4 bv = *(const f32x4*)&bt[d];
  u16x4 o;
  #pragma unroll
  for (int j = 0; j < 4; ++j) o[j] = f2bf(dv[j] * rstd * gv[j] + bv[j]);
  *(u16x4*)&xn[(size_t)t * 256 + d] = o;
}

// ---------- kernel 2: per-batch compaction (keys + per-branch queries) ----------
__global__ __launch_bounds__(1024) void compact_kernel(
    const int* __restrict__ labels, int* __restrict__ qidx_c,
    int* __restrict__ qidx_t, int* __restrict__ qcnt_c,
    int* __restrict__ qcnt_t, int* __restrict__ kidx,
    float* __restrict__ keyb, int* __restrict__ nktb,
    int* __restrict__ slotm)
{
  const int b = blockIdx.x, tid = threadIdx.x;
  const int wave = tid >> 6, lane = tid & 63;
  const bool ic = labels[b * 1024 + tid] > 0;
  const unsigned long long mask = __ballot(ic);
  const int lower = __popcll(mask & ((1ull << lane) - 1ull));
  const int wc = __popcll(mask);
  __shared__ int wcnt[16], woff[17];
  if (lane == 0) wcnt[wave] = wc;
  kidx[b * 1088 + tid] = b * 1028;       // pad defaults (register row 0)
  keyb[b * 1088 + tid] = -1e30f;
  if (tid < 64) { kidx[b * 1088 + 1024 + tid] = b * 1028;
                  keyb[b * 1088 + 1024 + tid] = -1e30f; }
  __syncthreads();
  if (tid == 0) {
    int acc = 0;
    #pragma unroll
    for (int i = 0; i < 16; ++i) { woff[i] = acc; acc += wcnt[i]; }
    woff[16] = acc;
  }
  __syncthreads();
  const int nc = woff[16];
  const int nt = 1024 - nc;
  const int rank_c = woff[wave] + lower;
  const int rank_t = tid - woff[wave] - lower;
  const int grow = b * 1028 + 4 + tid;
  if (ic) {
    qidx_c[b * 1024 + rank_c] = grow;
    slotm[b * 1024 + tid] = rank_c;
    kidx[b * 1088 + 4 + rank_c] = grow;
    keyb[b * 1088 + 4 + rank_c] = 0.0f;
  } else {
    qidx_t[b * 1024 + rank_t] = grow;
    slotm[b * 1024 + tid] = rank_t;
  }
  if (tid < 4) { kidx[b * 1088 + tid] = b * 1028 + tid;
                 keyb[b * 1088 + tid] = 0.0f; }
  const int ncp = (nc + 63) & ~63;
  const int ntp = (nt + 63) & ~63;
  if (tid >= nc && tid < ncp) qidx_c[b * 1024 + tid] = b * 1028;
  if (tid >= nt && tid < ntp) qidx_t[b * 1024 + tid] = b * 1028;
  if (tid == 0) {
    qcnt_c[b] = nc; qcnt_t[b] = nt;
    nktb[b] = (nc + 4 + 63) >> 6;
  }
}

// ---------- generic GEMM: C[M,N] = A[M,K] @ W[N,K]^T + bias ----------
template <int EPI, typename CT>
__global__ __launch_bounds__(256) void gemm_bt(
    const u16* __restrict__ A, int lda, const u16* __restrict__ W, int K,
    const float* __restrict__ bias, CT* __restrict__ C, int ldc, int M,
    const float* __restrict__ resid)
{
  const int mbase = blockIdx.y * 128, nbase = blockIdx.x * 128;
  __shared__ u16 As[128 * 32];
  __shared__ u16 Bs[128 * 32];
  const int tid = threadIdx.x, lane = tid & 63, w = tid >> 6;
  const int quad = lane >> 4, r = lane & 15;
  const int wm = w >> 1, wn = w & 1;
  const int rA = lane >> 2, cA = (lane & 3) * 8;

  f32x4 acc[4][4];
  #pragma unroll
  for (int i = 0; i < 4; ++i)
    #pragma unroll
    for (int j = 0; j < 4; ++j) acc[i][j] = (f32x4){0.f, 0.f, 0.f, 0.f};

  const int nkt = K >> 5;
  for (int kt = 0; kt < nkt; ++kt) {
    const int k0 = kt * 32;
    #pragma unroll
    for (int j = 0; j < 2; ++j) {
      const int rr = w * 32 + j * 16;
      g2lds16(&A[(size_t)(mbase + rr + rA) * lda + k0 + cA], &As[rr * 32]);
      g2lds16(&W[(size_t)(nbase + rr + rA) * K + k0 + cA], &Bs[rr * 32]);
    }
    __syncthreads();
    u16x8 av[4], bv[4];
    #pragma unroll
    for (int mi = 0; mi < 4; ++mi) av[mi] = ld8(&As[(wm * 64 + mi * 16 + r) * 32 + quad * 8]);
    #pragma unroll
    for (int ni = 0; ni < 4; ++ni) bv[ni] = ld8(&Bs[(wn * 64 + ni * 16 + r) * 32 + quad * 8]);
    #pragma unroll
    for (int mi = 0; mi < 4; ++mi)
      #pragma unroll
      for (int ni = 0; ni < 4; ++ni)
        acc[mi][ni] = mfma_bf16(av[mi], bv[ni], acc[mi][ni]);
    __syncthreads();
  }

  #pragma unroll
  for (int mi = 0; mi < 4; ++mi) {
    #pragma unroll
    for (int ni = 0; ni < 4; ++ni) {
      const int col = nbase + wn * 64 + ni * 16 + r;
      const float bs = bias[col];
      const int row0 = mbase + wm * 64 + mi * 16 + quad * 4;
      #pragma unroll
      for (int i = 0; i < 4; ++i) {
        const int rr2 = row0 + i;
        if (rr2 < M) {
          float v = acc[mi][ni][i] + bs;
          if (EPI == 1) v = 0.5f * v * (1.0f + erff(v * 0.70710678118654752f));
          if (EPI == 2) v += resid[(size_t)rr2 * ldc + col];
          stc(&C[(size_t)rr2 * ldc + col], v);
        }
      }
    }
  }
}

// ---------- Wo GEMM, both branches in one dispatch (z = branch) ----------
__global__ __launch_bounds__(256) void gemm_wo(
    const u16* __restrict__ Ac, const u16* __restrict__ At,
    const u16* __restrict__ Wc, const u16* __restrict__ Wt,
    const float* __restrict__ bc, const float* __restrict__ btg,
    u16* __restrict__ Cc, u16* __restrict__ Ct,
    const int* __restrict__ cnt_c, const int* __restrict__ cnt_t)
{
  const int z = blockIdx.z;
  const int mbase = blockIdx.y * 128, nbase = blockIdx.x * 128;
  const int* bcnt = z ? cnt_t : cnt_c;
  const int bb = mbase >> 10;
  const int need = (bcnt[bb] + 127) & ~127;
  if ((mbase & 1023) >= need) return;
  const u16* A = z ? At : Ac;
  const u16* W = z ? Wt : Wc;
  const float* bias = z ? btg : bc;
  u16* C = z ? Ct : Cc;

  __shared__ u16 As[128 * 32];
  __shared__ u16 Bs[128 * 32];
  const int tid = threadIdx.x, lane = tid & 63, w = tid >> 6;
  const int quad = lane >> 4, r = lane & 15;
  const int wm = w >> 1, wn = w & 1;
  const int rA = lane >> 2, cA = (lane & 3) * 8;

  f32x4 acc[4][4];
  #pragma unroll
  for (int i = 0; i < 4; ++i)
    #pragma unroll
    for (int j = 0; j < 4; ++j) acc[i][j] = (f32x4){0.f, 0.f, 0.f, 0.f};

  for (int kt = 0; kt < 8; ++kt) {
    const int k0 = kt * 32;
    #pragma unroll
    for (int j = 0; j < 2; ++j) {
      const int rr = w * 32 + j * 16;
      g2lds16(&A[(size_t)(mbase + rr + rA) * 256 + k0 + cA], &As[rr * 32]);
      g2lds16(&W[(size_t)(nbase + rr + rA) * 256 + k0 + cA], &Bs[rr * 32]);
    }
    __syncthreads();
    u16x8 av[4], bv[4];
    #pragma unroll
    for (int mi = 0; mi < 4; ++mi) av[mi] = ld8(&As[(wm * 64 + mi * 16 + r) * 32 + quad * 8]);
    #pragma unroll
    for (int ni = 0; ni < 4; ++ni) bv[ni] = ld8(&Bs[(wn * 64 + ni * 16 + r) * 32 + quad * 8]);
    #pragma unroll
    for (int mi = 0; mi < 4; ++mi)
      #pragma unroll
      for (int ni = 0; ni < 4; ++ni)
        acc[mi][ni] = mfma_bf16(av[mi], bv[ni], acc[mi][ni]);
    __syncthreads();
  }

  #pragma unroll
  for (int mi = 0; mi < 4; ++mi) {
    #pragma unroll
    for (int ni = 0; ni < 4; ++ni) {
      const int col = nbase + wn * 64 + ni * 16 + r;
      const float bs = bias[col];
      const int row0 = mbase + wm * 64 + mi * 16 + quad * 4;
      #pragma unroll
      for (int i = 0; i < 4; ++i) {
        const int rr2 = row0 + i;
        C[(size_t)rr2 * 256 + col] = f2bf(acc[mi][ni][i] + bs);
      }
    }
  }
}

// ---------- kernel 3: compacted flash attention, both branches (z) ----------
__global__ __launch_bounds__(256) void attn2_kernel(
    const u16* __restrict__ qkv, const float* __restrict__ bq_c,
    const float* __restrict__ bq_t, const int* __restrict__ qidx_c,
    const int* __restrict__ qidx_t, const int* __restrict__ qcnt_c,
    const int* __restrict__ qcnt_t, const int* __restrict__ kidx,
    const float* __restrict__ keyb, const int* __restrict__ nktb,
    u16* __restrict__ o_c, u16* __restrict__ o_t)
{
  const int qb = blockIdx.x, h = blockIdx.y, z = blockIdx.z;
  const int b = qb >> 4, qb_in = qb & 15;
  const int* qcnt = z ? qcnt_t : qcnt_c;
  if (qb_in * 64 >= qcnt[b]) return;
  const float* bqkv = z ? bq_t : bq_c;
  const int* qidx = z ? qidx_t : qidx_c;
  u16* obuf = z ? o_t : o_c;
  const u16* qz = qkv + z * 768;

  const int tid = threadIdx.x, lane = tid & 63, w = tid >> 6;
  const int quad = lane >> 4, r = lane & 15;
  const float scale = 0.17677669529663687f;  // 1/sqrt(32)

  __shared__ u16 Ks[64 * 32];        // [key][dim]
  __shared__ u16 Vt[32 * 66];        // [dim][key] stride 66
  __shared__ u16 Ps[4][16 * 72];     // per-wave P [q][key] stride 72
  __shared__ float keybS[64];

  const int qslot = qb_in * 64 + w * 16 + r;
  const int qrow = qidx[b * 1024 + qslot];
  const u16x8 qf = ld8(&qz[(size_t)qrow * 1536 + h * 32 + quad * 8]);

  float s0 = 0.f;
  #pragma unroll
  for (int j = 0; j < 8; ++j) s0 += bf2f(qf[j]) * bqkv[256 + h * 32 + quad * 8 + j];
  s0 *= scale;
  s0 += __shfl_xor(s0, 16);
  s0 += __shfl_xor(s0, 32);
  float m_ = s0, l_ = 1.0f;
  f32x4 accA, accB;
  #pragma unroll
  for (int i = 0; i < 4; ++i) {
    accA[i] = bqkv[512 + h * 32 + quad * 4 + i];
    accB[i] = bqkv[512 + h * 32 + 16 + quad * 4 + i];
  }

  const int key = tid >> 2, dc = (tid & 3) * 8;
  const int ntile = nktb[b];
  for (int t = 0; t < ntile; ++t) {
    __syncthreads();
    const int krow = kidx[b * 1088 + t * 64 + key];
    g2lds16(&qz[(size_t)krow * 1536 + 256 + h * 32 + dc], &Ks[w * 512]);
    const u16x8 vv = ld8(&qz[(size_t)krow * 1536 + 512 + h * 32 + dc]);
    #pragma unroll
    for (int j = 0; j < 8; ++j) Vt[(dc + j) * 66 + key] = vv[j];
    if (tid < 64) keybS[tid] = keyb[b * 1088 + t * 64 + tid];
    __syncthreads();

    f32x4 sT[4];
    #pragma unroll
    for (int tt = 0; tt < 4; ++tt) {
      const u16x8 kf = ld8(&Ks[(tt * 16 + r) * 32 + quad * 8]);
      sT[tt] = mfma_bf16(kf, qf, (f32x4){0.f, 0.f, 0.f, 0.f});
    }
    float rm = -3.0e38f;
    float sc[4][4];
    #pragma unroll
    for (int tt = 0; tt < 4; ++tt)
      #pragma unroll
      for (int i = 0; i < 4; ++i) {
        sc[tt][i] = sT[tt][i] * scale + keybS[tt * 16 + quad * 4 + i];
        rm = fmaxf(rm, sc[tt][i]);
      }
    rm = fmaxf(rm, __shfl_xor(rm, 16));
    rm = fmaxf(rm, __shfl_xor(rm, 32));
    const float mn = fmaxf(m_, rm);
    const float al = __expf(m_ - mn);
    m_ = mn;
    float rs = 0.f;
    u16* ps = &Ps[w][r * 72];
    #pragma unroll
    for (int tt = 0; tt < 4; ++tt) {
      u16x4 pk;
      #pragma unroll
      for (int i = 0; i < 4; ++i) {
        const float pv = __expf(sc[tt][i] - mn);
        rs += pv;
        pk[i] = f2bf(pv);
      }
      *(u16x4*)&ps[tt * 16 + quad * 4] = pk;
    }
    rs += __shfl_xor(rs, 16);
    rs += __shfl_xor(rs, 32);
    l_ = l_ * al + rs;
    #pragma unroll
    for (int i = 0; i < 4; ++i) { accA[i] *= al; accB[i] *= al; }
    #pragma unroll
    for (int kk = 0; kk < 2; ++kk) {
      const u16x8 pf = ld8(&Ps[w][r * 72 + kk * 32 + quad * 8]);
      const u16x8 vf0 = ld8(&Vt[r * 66 + kk * 32 + quad * 8]);
      const u16x8 vf1 = ld8(&Vt[(16 + r) * 66 + kk * 32 + quad * 8]);
      accA = mfma_bf16(vf0, pf, accA);
      accB = mfma_bf16(vf1, pf, accB);
    }
  }

  const float inv = 1.0f / l_;
  u16x4 oa, ob;
  #pragma unroll
  for (int i = 0; i < 4; ++i) { oa[i] = f2bf(accA[i] * inv); ob[i] = f2bf(accB[i] * inv); }
  const size_t orow = (size_t)b * 1024 + qslot;
  *(u16x4*)&obuf[orow * 256 + h * 32 + quad * 4] = oa;
  *(u16x4*)&obuf[orow * 256 + h * 32 + 16 + quad * 4] = ob;
}

// ---------- kernel 4: branch select + residual + LN (wave-per-row) ----------
__global__ __launch_bounds__(256) void select_ln_kernel(
    const float* __restrict__ x0, const u16* __restrict__ po_c,
    const u16* __restrict__ po_t, const int* __restrict__ labels,
    const int* __restrict__ slotm, const float* __restrict__ g,
    const float* __restrict__ bt, float* __restrict__ x1,
    u16* __restrict__ hln)
{
  const int wv = threadIdx.x >> 6, lane = threadIdx.x & 63;
  const int t = blockIdx.x * 4 + wv;          // 0..8191
  const int d = lane * 4;
  const int b = t >> 10;
  const size_t row = (size_t)b * 1028 + 4 + (t & 1023);
  const bool ic = labels[t] > 0;
  const u16* po = ic ? po_c : po_t;
  const int slot = slotm[t];
  const f32x4 xv = *(const f32x4*)&x0[row * 256 + d];
  const u16x4 pv = *(const u16x4*)&po[((size_t)b * 1024 + slot) * 256 + d];
  f32x4 v;
  #pragma unroll
  for (int j = 0; j < 4; ++j) v[j] = xv[j] + bf2f(pv[j]);
  *(f32x4*)&x1[(size_t)t * 256 + d] = v;
  float s1 = v[0] + v[1] + v[2] + v[3];
  #pragma unroll
  for (int off = 1; off < 64; off <<= 1) s1 += __shfl_xor(s1, off);
  const float mean = s1 * (1.0f / 256.0f);
  f32x4 dv;
  float s2 = 0.f;
  #pragma unroll
  for (int j = 0; j < 4; ++j) { dv[j] = v[j] - mean; s2 += dv[j] * dv[j]; }
  #pragma unroll
  for (int off = 1; off < 64; off <<= 1) s2 += __shfl_xor(s2, off);
  const float rstd = rsqrtf(s2 * (1.0f / 256.0f) + 1e-5f);
  const f32x4 gv = *(const f32x4*)&g[d];
  const f32x4 bv = *(const f32x4*)&bt[d];
  u16x4 o;
  #pragma unroll
  for (int j = 0; j < 4; ++j) o[j] = f2bf(dv[j] * rstd * gv[j] + bv[j]);
  *(u16x4*)&hln[(size_t)t * 256 + d] = o;
}

// ---------- launch ----------
extern "C" void kernel_launch(void* const* d_in, const int* in_sizes, int n_in,
                              void* d_out, int out_size, void* d_ws, size_t ws_size,
                              hipStream_t stream) {
  const float* x      = (const float*)d_in[0];
  const int*   coords = (const int*)d_in[1];
  const int*   labels = (const int*)d_in[2];
  const float* tgt_e  = (const float*)d_in[3];
  const float* ctx_e  = (const float*)d_in[4];
  const float* regs   = (const float*)d_in[5];
  const float* rope   = (const float*)d_in[6];
  const float* ng     = (const float*)d_in[7];
  const float* nb     = (const float*)d_in[8];
  const float* cWqkv  = (const float*)d_in[9];
  const float* cbqkv  = (const float*)d_in[10];
  const float* cWo    = (const float*)d_in[11];
  const float* cbo    = (const float*)d_in[12];
  const float* tWqkv  = (const float*)d_in[13];
  const float* tbqkv  = (const float*)d_in[14];
  const float* tWo    = (const float*)d_in[15];
  const float* tbo    = (const float*)d_in[16];
  const float* mg     = (const float*)d_in[17];
  const float* mbeta  = (const float*)d_in[18];
  const float* W1     = (const float*)d_in[19];
  const float* b1     = (const float*)d_in[20];
  const float* W2     = (const float*)d_in[21];
  const float* b2     = (const float*)d_in[22];

  char* ws = (char*)d_ws;
  float* x0     = (float*)(ws + 0);            // 8224x256 f32
  u16*   xn     = (u16*)  (ws + 8421376);      // 8320x256 bf16
  u16*   wq_ct  = (u16*)  (ws + 12681216);     // 1536x256 bf16
  float* biasq  = (float*)(ws + 13467648);     // 1536 f32
  u16*   woc    = (u16*)  (ws + 13473792);     // 256x256
  u16*   wot    = (u16*)  (ws + 13604864);
  u16*   w1b    = (u16*)  (ws + 13735936);     // 1024x256
  u16*   w2b    = (u16*)  (ws + 14260224);     // 256x1024 -> 14,784,512
  u16*   qkv    = (u16*)  (ws + 14784512);     // 8320x1536 -> 40,343,552
  u16*   o_c    = (u16*)  (ws + 40343552);     // 8192x256 -> 44,537,856
  u16*   o_t    = (u16*)  (ws + 44537856);     //          -> 48,732,160
  float* x1     = (float*)(ws + 48732160);     // 8192x256 f32 -> 57,120,768
  u16*   hln    = (u16*)  (ws + 57120768);     // 8192x256 -> 61,315,072
  int*   qidx_c = (int*)  (ws + 61315072);     // 8192 int
  int*   qidx_t = (int*)  (ws + 61347840);
  int*   kidx   = (int*)  (ws + 61380608);     // 8x1088
  float* keyb   = (float*)(ws + 61415424);     // 8x1088
  int*   slotm  = (int*)  (ws + 61450240);     // 8192
  int*   qcnt_c = (int*)  (ws + 61483008);     // 8
  int*   qcnt_t = (int*)  (ws + 61483040);     // 8
  int*   nktb   = (int*)  (ws + 61483072);     // 8
  // aliases into dead qkv region (qkv consumed by attn before these writes):
  u16*   po_c   = (u16*)  (ws + 14784512);     // 8192x256
  u16*   po_t   = (u16*)  (ws + 18978816);
  u16*   hmid   = (u16*)  (ws + 23173120);     // 8192x1024 -> 39,950,336

  cvt_kernel<<<dim3(1026), 256, 0, stream>>>(
      cWqkv, tWqkv, cWo, tWo, W1, W2,
      wq_ct, wq_ct + 768 * 256, woc, wot, w1b, w2b, cbqkv, tbqkv, biasq);
  prep_kernel<<<dim3(2080), 256, 0, stream>>>(x, coords, labels, tgt_e, ctx_e,
                                              regs, rope, ng, nb, x0, xn);
  compact_kernel<<<dim3(8), 1024, 0, stream>>>(labels, qidx_c, qidx_t, qcnt_c,
                                               qcnt_t, kidx, keyb, nktb, slotm);
  gemm_bt<0, u16><<<dim3(12, 65), 256, 0, stream>>>(xn, 256, wq_ct, 256, biasq, qkv, 1536, 8320, nullptr);
  attn2_kernel<<<dim3(128, 8, 2), 256, 0, stream>>>(qkv, cbqkv, tbqkv, qidx_c, qidx_t,
                                                    qcnt_c, qcnt_t, kidx, keyb, nktb, o_c, o_t);
  gemm_wo<<<dim3(2, 64, 2), 256, 0, stream>>>(o_c, o_t, woc, wot, cbo, tbo, po_c, po_t, qcnt_c, qcnt_t);
  select_ln_kernel<<<dim3(2048), 256, 0, stream>>>(x0, po_c, po_t, labels, slotm, mg, mbeta, x1, hln);
  gemm_bt<1, u16><<<dim3(8, 64), 256, 0, stream>>>(hln, 256, w1b, 256, b1, hmid, 1024, 8192, nullptr);
  gemm_bt<2, float><<<dim3(2, 64), 256, 0, stream>>>(hmid, 1024, w2b, 1024, b2, (float*)d_out, 256, 8192, x1);
}